// Round 11
// baseline (5792.584 us; speedup 1.0000x reference)
//
#include <hip/hip_runtime.h>
#include <math.h>

// RNN scan, SEQ=2048, BATCH=64, I=H=O=256, fp32.
// GOLDEN (confirmed round 10, absmax 0.0): XLA-CPU fp32 —
//   dots : per-element single-acc ascending-k FMA chain (Eigen gebp)
//   +bh, +xp : one fadd each
//   tanh : Eigen fast-tanh, clamp +-7.99881172180175781, FMA Horner,
//          exact fdiv, |x|<4e-4 -> x (unclamped).
// DO NOT change op order in K1/K2 — the recurrence is chaotic (gain ~2.5/step).
// K3 (outside the loop) is free-form fp32 (2% tolerance).
//
// R11 scan restructure (order-preserving, perf only):
//   - store h_{t-1} / load xp_{t+1} issued at TOP of step -> retire under the
//     1024-cyc dependent FMA chain instead of stalling at the barrier.
//   - double-buffered h in LDS -> ONE barrier per step.
//   - ds_read_b128 h reads (64 instrs instead of 256; same FMA order).

#define SEQ 2048
#define BATCH 64
#define HID 256
#define BH 16384  // BATCH*HID

// Eigen/XLA fast-tanh f32, FMA evaluation, clamp 7.99881172180175781.
__device__ __forceinline__ float tanh_xla(float x) {
  const float kClamp = 7.99881172180175781f;
  float xc = fminf(fmaxf(x, -kClamp), kClamp);
  float x2 = __fmul_rn(xc, xc);
  float p = __fmaf_rn(x2, -2.76076847742355e-16f, 2.00018790482477e-13f);
  p = __fmaf_rn(x2, p, -8.60467152213735e-11f);
  p = __fmaf_rn(x2, p, 5.12229709037114e-08f);
  p = __fmaf_rn(x2, p, 1.48572235717979e-05f);
  p = __fmaf_rn(x2, p, 6.37261928875436e-04f);
  p = __fmaf_rn(x2, p, 4.89352455891786e-03f);
  p = __fmul_rn(xc, p);
  float q = __fmaf_rn(x2, 1.19825839466702e-06f, 1.18534705686654e-04f);
  q = __fmaf_rn(x2, q, 2.26843463243900e-03f);
  q = __fmaf_rn(x2, q, 4.89352518554385e-03f);
  float r = __fdiv_rn(p, q);
  return (fabsf(x) < 0.0004f) ? x : r;
}

// ---------------------------------------------------------------------------
// K1: xp = X @ Ux + bh. Per element: single-acc ascending-i FMA chain
// (Eigen order), then one fadd for bias. BIT-EXACT — do not reorder.
// ---------------------------------------------------------------------------
__global__ __launch_bounds__(256) void xp_dot_kernel(
    const float* __restrict__ X, const float* __restrict__ Ux,
    const float* __restrict__ bh, float* __restrict__ XP) {
  __shared__ float xs[8][256];

  const int tid = threadIdx.x;
  const size_t row0 = (size_t)blockIdx.x * 8;

  const float4* src = (const float4*)(X + row0 * 256);
  float4* dst = (float4*)&xs[0][0];
  dst[tid] = src[tid];
  dst[256 + tid] = src[256 + tid];
  __syncthreads();

  const int h = tid;
  float acc[8] = {0.f, 0.f, 0.f, 0.f, 0.f, 0.f, 0.f, 0.f};

#pragma unroll 4
  for (int i = 0; i < 256; ++i) {
    float u = Ux[i * 256 + h];
#pragma unroll
    for (int r = 0; r < 8; ++r)
      acc[r] = __fmaf_rn(xs[r][i], u, acc[r]);   // ascending i, single acc
  }

  const float b = bh[h];
#pragma unroll
  for (int r = 0; r < 8; ++r)
    XP[(row0 + r) * 256 + h] = __fadd_rn(acc[r], b);
}

// ---------------------------------------------------------------------------
// K2: scan. One block per batch row; thread j owns column j, Wh[:,j] in
// registers. Per step (single barrier, double-buffered h):
//   [issue store h_{t-1} -> HBM]  [issue load xp_{t+1}]   (hide under chain)
//   acc = ascending-k FMA chain over cur h buffer (ds_read_b128 x64)
//   z = fadd(xp_t, acc); hn = tanh_xla(z); nxt[j] = hn; barrier; swap.
// ---------------------------------------------------------------------------
__global__ __launch_bounds__(256, 1) void scan_xla_kernel(
    const float* __restrict__ Wh, const float* __restrict__ h0,
    float* __restrict__ xpH, float* __restrict__ hfinal) {
  __shared__ float hbuf0[256];
  __shared__ float hbuf1[256];

  const int b = blockIdx.x;
  const int j = threadIdx.x;

  float w[256];
#pragma unroll
  for (int k = 0; k < 256; ++k) w[k] = Wh[k * 256 + j];  // column j

  hbuf0[j] = h0[b * 256 + j];
  __syncthreads();

  float xp_cur = xpH[(size_t)b * 256 + j];  // xp[t=0]
  float hn_prev = 0.f;                      // h_{t-1}[j], valid for t>=1
  const float* cur = hbuf0;
  float* nxt = hbuf1;

  for (int t = 0; t < SEQ; ++t) {
    // Issue previous h-store and next xp-load FIRST: ~500-900 cyc of HBM
    // latency retires under the ~1024-cyc dependent FMA chain below.
    if (t > 0)
      xpH[(size_t)(t - 1) * BH + b * 256 + j] = hn_prev;
    float xp_next = (t + 1 < SEQ) ? xpH[(size_t)(t + 1) * BH + b * 256 + j] : 0.f;

    // (h @ Wh)[j]: single acc, ascending k — BIT-EXACT order.
    float acc = 0.f;
    const float4* h4 = (const float4*)cur;
#pragma unroll
    for (int k4 = 0; k4 < 64; ++k4) {
      float4 hv = h4[k4];
      acc = __fmaf_rn(hv.x, w[k4 * 4 + 0], acc);
      acc = __fmaf_rn(hv.y, w[k4 * 4 + 1], acc);
      acc = __fmaf_rn(hv.z, w[k4 * 4 + 2], acc);
      acc = __fmaf_rn(hv.w, w[k4 * 4 + 3], acc);
    }

    float z = __fadd_rn(xp_cur, acc);
    float hn = tanh_xla(z);

    nxt[j] = hn;          // writes go to the buffer nobody reads this step
    __syncthreads();      // one barrier: writes visible, loads/stores drained

    const float* tmp = cur; cur = nxt; nxt = (float*)tmp;
    xp_cur = xp_next;
    hn_prev = hn;
  }

  xpH[(size_t)(SEQ - 1) * BH + b * 256 + j] = hn_prev;
  hfinal[b * 256 + j] = hn_prev;
}

// ---------------------------------------------------------------------------
// K3: in-place fp32 GEMM: rows of HO (M x 256) -> row @ Vo + co.
// Outside the feedback loop => rounding free. Block stages its own 64 rows
// in LDS then overwrites exactly those rows (race-free).
// ---------------------------------------------------------------------------
__global__ __launch_bounds__(256) void gemm_inplace_kernel(
    float* __restrict__ HO, const float* __restrict__ Vo,
    const float* __restrict__ co) {
  __shared__ float Hs[64][260];
  __shared__ float Bs[32][64];

  const int tid = threadIdx.x;
  const int bm = blockIdx.x;
  float* base = HO + (size_t)bm * 64 * 256;

#pragma unroll
  for (int l = 0; l < 16; ++l) {
    int idx = l * 256 + tid;
    int r = idx >> 6;
    int c4 = idx & 63;
    float4 v = *(const float4*)&base[r * 256 + c4 * 4];
    *(float4*)&Hs[r][c4 * 4] = v;
  }

  const int tr = tid >> 4;
  const int tc = tid & 15;

  for (int bn = 0; bn < 4; ++bn) {
    float acc[4][4];
#pragma unroll
    for (int i = 0; i < 4; ++i)
#pragma unroll
      for (int j = 0; j < 4; ++j) acc[i][j] = 0.f;

    for (int kt = 0; kt < 256; kt += 32) {
      __syncthreads();
#pragma unroll
      for (int l = 0; l < 2; ++l) {
        int idx = tid * 2 + l;
        int k2 = idx >> 4;
        int nn = (idx & 15) << 2;
        float4 bv = *(const float4*)&Vo[(size_t)(kt + k2) * 256 + bn * 64 + nn];
        *(float4*)&Bs[k2][nn] = bv;
      }
      __syncthreads();
#pragma unroll
      for (int k = 0; k < 32; ++k) {
        float4 bq = *(const float4*)&Bs[k][tc * 4];
        float bv[4] = {bq.x, bq.y, bq.z, bq.w};
#pragma unroll
        for (int i = 0; i < 4; ++i) {
          float a = Hs[tr * 4 + i][kt + k];
#pragma unroll
          for (int j = 0; j < 4; ++j) acc[i][j] += a * bv[j];
        }
      }
    }

    const float4 cb = *(const float4*)&co[bn * 64 + tc * 4];
    const float cv[4] = {cb.x, cb.y, cb.z, cb.w};
#pragma unroll
    for (int i = 0; i < 4; ++i) {
      float4 o;
      o.x = acc[i][0] + cv[0];
      o.y = acc[i][1] + cv[1];
      o.z = acc[i][2] + cv[2];
      o.w = acc[i][3] + cv[3];
      *(float4*)&base[(tr * 4 + i) * 256 + bn * 64 + tc * 4] = o;
    }
  }
}

extern "C" void kernel_launch(void* const* d_in, const int* in_sizes, int n_in,
                              void* d_out, int out_size, void* d_ws, size_t ws_size,
                              hipStream_t stream) {
  const float* inputs = (const float*)d_in[0];
  const float* h0     = (const float*)d_in[1];
  const float* Wh     = (const float*)d_in[2];
  const float* Ux     = (const float*)d_in[3];
  const float* bh     = (const float*)d_in[4];
  const float* Vo     = (const float*)d_in[5];
  const float* co     = (const float*)d_in[6];

  float* out = (float*)d_out;                       // outputs (S,B,O)
  float* hfinal = out + (size_t)SEQ * BATCH * 256;  // ht_final (B,H)
  (void)d_ws; (void)ws_size;

  const int M = SEQ * BATCH;  // 131072 rows

  // K1: xp (Eigen-order FMA chain + bias add) -> d_out outputs region
  xp_dot_kernel<<<M / 8, 256, 0, stream>>>(inputs, Ux, bh, out);

  // K2: XLA-exact scan (restructured: hidden store/load, 1 barrier/step).
  scan_xla_kernel<<<BATCH, 256, 0, stream>>>(Wh, h0, out, hfinal);

  // K3: in-place outputs = H @ Vo + co.
  gemm_inplace_kernel<<<M / 64, 256, 0, stream>>>(out, Vo, co);
}

// Round 12
// 5786.565 us; speedup vs baseline: 1.0010x; 1.0010x over previous
//
#include <hip/hip_runtime.h>
#include <math.h>

// RNN scan, SEQ=2048, BATCH=64, I=H=O=256, fp32.
// GOLDEN (confirmed round 10, absmax 0.0): XLA-CPU fp32 —
//   dots : per-element single-acc ascending-k FMA chain (Eigen gebp)
//   +bh, +xp : one fadd each
//   tanh : Eigen fast-tanh, clamp +-7.99881172180175781, FMA Horner,
//          exact fdiv, |x|<4e-4 -> x (unclamped).
// DO NOT change op order in K1/K2 — the recurrence is chaotic (gain ~2.5/step).
//
// R12: R10/R11 had VGPR_Count=136 => w[256] was in SCRATCH (runtime-indexed
// array, rule #20), ~5800 cyc/step of exposed L2 latency. This round the 256
// weights live in 64 explicitly-NAMED float4 registers (macro-generated,
// every index a literal). Same FMA order bit-exactly.

#define SEQ 2048
#define BATCH 64
#define HID 256
#define BH 16384  // BATCH*HID

// Eigen/XLA fast-tanh f32, FMA evaluation, clamp 7.99881172180175781.
__device__ __forceinline__ float tanh_xla(float x) {
  const float kClamp = 7.99881172180175781f;
  float xc = fminf(fmaxf(x, -kClamp), kClamp);
  float x2 = __fmul_rn(xc, xc);
  float p = __fmaf_rn(x2, -2.76076847742355e-16f, 2.00018790482477e-13f);
  p = __fmaf_rn(x2, p, -8.60467152213735e-11f);
  p = __fmaf_rn(x2, p, 5.12229709037114e-08f);
  p = __fmaf_rn(x2, p, 1.48572235717979e-05f);
  p = __fmaf_rn(x2, p, 6.37261928875436e-04f);
  p = __fmaf_rn(x2, p, 4.89352455891786e-03f);
  p = __fmul_rn(xc, p);
  float q = __fmaf_rn(x2, 1.19825839466702e-06f, 1.18534705686654e-04f);
  q = __fmaf_rn(x2, q, 2.26843463243900e-03f);
  q = __fmaf_rn(x2, q, 4.89352518554385e-03f);
  float r = __fdiv_rn(p, q);
  return (fabsf(x) < 0.0004f) ? x : r;
}

// ---------------------------------------------------------------------------
// K1: xp = X @ Ux + bh. Per element: single-acc ascending-i FMA chain
// (Eigen order), then one fadd for bias. BIT-EXACT — do not reorder.
// ---------------------------------------------------------------------------
__global__ __launch_bounds__(256) void xp_dot_kernel(
    const float* __restrict__ X, const float* __restrict__ Ux,
    const float* __restrict__ bh, float* __restrict__ XP) {
  __shared__ float xs[8][256];

  const int tid = threadIdx.x;
  const size_t row0 = (size_t)blockIdx.x * 8;

  const float4* src = (const float4*)(X + row0 * 256);
  float4* dst = (float4*)&xs[0][0];
  dst[tid] = src[tid];
  dst[256 + tid] = src[256 + tid];
  __syncthreads();

  const int h = tid;
  float acc[8] = {0.f, 0.f, 0.f, 0.f, 0.f, 0.f, 0.f, 0.f};

#pragma unroll 4
  for (int i = 0; i < 256; ++i) {
    float u = Ux[i * 256 + h];
#pragma unroll
    for (int r = 0; r < 8; ++r)
      acc[r] = __fmaf_rn(xs[r][i], u, acc[r]);   // ascending i, single acc
  }

  const float b = bh[h];
#pragma unroll
  for (int r = 0; r < 8; ++r)
    XP[(row0 + r) * 256 + h] = __fadd_rn(acc[r], b);
}

// ---------------------------------------------------------------------------
// K2: scan. One block per batch row; thread j owns column j. Wh[:,j] in 64
// NAMED float4 registers (no arrays -> no scratch). Per step: issue h-store/
// xp-load first (hide under chain), 256-FMA ascending-k chain from LDS
// (double-buffered), tanh, one barrier.
// ---------------------------------------------------------------------------
#define DCL(A,B) float4 wq##A##B;
#define DCLROW(A) DCL(A,0) DCL(A,1) DCL(A,2) DCL(A,3) DCL(A,4) DCL(A,5) DCL(A,6) DCL(A,7)

#define LDW(A,B) { const int k0 = ((A)*8+(B))*4; \
  wq##A##B.x = Wh[(k0+0)*256 + j]; \
  wq##A##B.y = Wh[(k0+1)*256 + j]; \
  wq##A##B.z = Wh[(k0+2)*256 + j]; \
  wq##A##B.w = Wh[(k0+3)*256 + j]; }
#define LDWROW(A) LDW(A,0) LDW(A,1) LDW(A,2) LDW(A,3) LDW(A,4) LDW(A,5) LDW(A,6) LDW(A,7)

#define ACC4(A,B) { float4 hv = h4[(A)*8+(B)]; \
  acc = __fmaf_rn(hv.x, wq##A##B.x, acc); \
  acc = __fmaf_rn(hv.y, wq##A##B.y, acc); \
  acc = __fmaf_rn(hv.z, wq##A##B.z, acc); \
  acc = __fmaf_rn(hv.w, wq##A##B.w, acc); }
#define ACCROW(A) ACC4(A,0) ACC4(A,1) ACC4(A,2) ACC4(A,3) ACC4(A,4) ACC4(A,5) ACC4(A,6) ACC4(A,7)

__global__ __launch_bounds__(256, 1) void scan_xla_kernel(
    const float* __restrict__ Wh, const float* __restrict__ h0,
    float* __restrict__ xpH, float* __restrict__ hfinal) {
  __shared__ float hbuf0[256];
  __shared__ float hbuf1[256];

  const int b = blockIdx.x;
  const int j = threadIdx.x;

  DCLROW(0) DCLROW(1) DCLROW(2) DCLROW(3)
  DCLROW(4) DCLROW(5) DCLROW(6) DCLROW(7)

  LDWROW(0) LDWROW(1) LDWROW(2) LDWROW(3)
  LDWROW(4) LDWROW(5) LDWROW(6) LDWROW(7)

  hbuf0[j] = h0[b * 256 + j];
  __syncthreads();

  float xp_cur = xpH[(size_t)b * 256 + j];  // xp[t=0]
  float hn_prev = 0.f;                      // h_{t-1}[j], valid for t>=1
  const float* cur = hbuf0;
  float* nxt = hbuf1;

  for (int t = 0; t < SEQ; ++t) {
    // Issue previous h-store and next xp-load FIRST: HBM latency retires
    // under the ~1024-cyc dependent FMA chain below.
    if (t > 0)
      xpH[(size_t)(t - 1) * BH + b * 256 + j] = hn_prev;
    float xp_next = (t + 1 < SEQ) ? xpH[(size_t)(t + 1) * BH + b * 256 + j] : 0.f;

    // (h @ Wh)[j]: single acc, ascending k — BIT-EXACT order.
    float acc = 0.f;
    const float4* h4 = (const float4*)cur;
    ACCROW(0) ACCROW(1) ACCROW(2) ACCROW(3)
    ACCROW(4) ACCROW(5) ACCROW(6) ACCROW(7)

    float z = __fadd_rn(xp_cur, acc);
    float hn = tanh_xla(z);

    nxt[j] = hn;          // write to the buffer nobody reads this step
    __syncthreads();      // one barrier per step

    const float* tmp = cur; cur = nxt; nxt = (float*)tmp;
    xp_cur = xp_next;
    hn_prev = hn;
  }

  xpH[(size_t)(SEQ - 1) * BH + b * 256 + j] = hn_prev;
  hfinal[b * 256 + j] = hn_prev;
}

// ---------------------------------------------------------------------------
// K3: in-place fp32 GEMM: rows of HO (M x 256) -> row @ Vo + co.
// Outside the feedback loop => rounding free. Block stages its own 64 rows
// in LDS then overwrites exactly those rows (race-free).
// ---------------------------------------------------------------------------
__global__ __launch_bounds__(256) void gemm_inplace_kernel(
    float* __restrict__ HO, const float* __restrict__ Vo,
    const float* __restrict__ co) {
  __shared__ float Hs[64][260];
  __shared__ float Bs[32][64];

  const int tid = threadIdx.x;
  const int bm = blockIdx.x;
  float* base = HO + (size_t)bm * 64 * 256;

#pragma unroll
  for (int l = 0; l < 16; ++l) {
    int idx = l * 256 + tid;
    int r = idx >> 6;
    int c4 = idx & 63;
    float4 v = *(const float4*)&base[r * 256 + c4 * 4];
    *(float4*)&Hs[r][c4 * 4] = v;
  }

  const int tr = tid >> 4;
  const int tc = tid & 15;

  for (int bn = 0; bn < 4; ++bn) {
    float acc[4][4];
#pragma unroll
    for (int i = 0; i < 4; ++i)
#pragma unroll
      for (int j = 0; j < 4; ++j) acc[i][j] = 0.f;

    for (int kt = 0; kt < 256; kt += 32) {
      __syncthreads();
#pragma unroll
      for (int l = 0; l < 2; ++l) {
        int idx = tid * 2 + l;
        int k2 = idx >> 4;
        int nn = (idx & 15) << 2;
        float4 bv = *(const float4*)&Vo[(size_t)(kt + k2) * 256 + bn * 64 + nn];
        *(float4*)&Bs[k2][nn] = bv;
      }
      __syncthreads();
#pragma unroll
      for (int k = 0; k < 32; ++k) {
        float4 bq = *(const float4*)&Bs[k][tc * 4];
        float bv[4] = {bq.x, bq.y, bq.z, bq.w};
#pragma unroll
        for (int i = 0; i < 4; ++i) {
          float a = Hs[tr * 4 + i][kt + k];
#pragma unroll
          for (int j = 0; j < 4; ++j) acc[i][j] += a * bv[j];
        }
      }
    }

    const float4 cb = *(const float4*)&co[bn * 64 + tc * 4];
    const float cv[4] = {cb.x, cb.y, cb.z, cb.w};
#pragma unroll
    for (int i = 0; i < 4; ++i) {
      float4 o;
      o.x = acc[i][0] + cv[0];
      o.y = acc[i][1] + cv[1];
      o.z = acc[i][2] + cv[2];
      o.w = acc[i][3] + cv[3];
      *(float4*)&base[(tr * 4 + i) * 256 + bn * 64 + tc * 4] = o;
    }
  }
}

extern "C" void kernel_launch(void* const* d_in, const int* in_sizes, int n_in,
                              void* d_out, int out_size, void* d_ws, size_t ws_size,
                              hipStream_t stream) {
  const float* inputs = (const float*)d_in[0];
  const float* h0     = (const float*)d_in[1];
  const float* Wh     = (const float*)d_in[2];
  const float* Ux     = (const float*)d_in[3];
  const float* bh     = (const float*)d_in[4];
  const float* Vo     = (const float*)d_in[5];
  const float* co     = (const float*)d_in[6];

  float* out = (float*)d_out;                       // outputs (S,B,O)
  float* hfinal = out + (size_t)SEQ * BATCH * 256;  // ht_final (B,H)
  (void)d_ws; (void)ws_size;

  const int M = SEQ * BATCH;  // 131072 rows

  // K1: xp (Eigen-order FMA chain + bias add) -> d_out outputs region
  xp_dot_kernel<<<M / 8, 256, 0, stream>>>(inputs, Ux, bh, out);

  // K2: XLA-exact scan, weights in named registers.
  scan_xla_kernel<<<BATCH, 256, 0, stream>>>(Wh, h0, out, hfinal);

  // K3: in-place outputs = H @ Vo + co.
  gemm_inplace_kernel<<<M / 64, 256, 0, stream>>>(out, Vo, co);
}

// Round 13
// 5668.330 us; speedup vs baseline: 1.0219x; 1.0209x over previous
//
#include <hip/hip_runtime.h>
#include <math.h>

// RNN scan, SEQ=2048, BATCH=64, I=H=O=256, fp32.
// GOLDEN (confirmed round 10, absmax 0.0): XLA-CPU fp32 —
//   dots : per-element single-acc ascending-k FMA chain (Eigen gebp)
//   +bh, +xp : one fadd each
//   tanh : Eigen fast-tanh, clamp +-7.99881172180175781, FMA Horner,
//          exact fdiv, |x|<4e-4 -> x (unclamped).
// DO NOT change op order in K1/K2 — the recurrence is chaotic (gain ~2.5/step).
//
// R13: R11/R12 scan stuck at 5035us with VGPR_Count=136 -> weights were being
// spilled/rematerialized through L2 every step (~5900 cyc/step). Fix:
//   (a) amdgpu_waves_per_eu(1,1): allow up to 512 VGPR/wave (1 wave/SIMD).
//   (b) opaque-ify loaded weights with empty inline asm ("+v") so the
//       compiler CANNOT rematerialize them from memory; must keep in VGPRs.
// Arithmetic identical; only register placement changes.

#define SEQ 2048
#define BATCH 64
#define HID 256
#define BH 16384  // BATCH*HID

// Eigen/XLA fast-tanh f32, FMA evaluation, clamp 7.99881172180175781.
__device__ __forceinline__ float tanh_xla(float x) {
  const float kClamp = 7.99881172180175781f;
  float xc = fminf(fmaxf(x, -kClamp), kClamp);
  float x2 = __fmul_rn(xc, xc);
  float p = __fmaf_rn(x2, -2.76076847742355e-16f, 2.00018790482477e-13f);
  p = __fmaf_rn(x2, p, -8.60467152213735e-11f);
  p = __fmaf_rn(x2, p, 5.12229709037114e-08f);
  p = __fmaf_rn(x2, p, 1.48572235717979e-05f);
  p = __fmaf_rn(x2, p, 6.37261928875436e-04f);
  p = __fmaf_rn(x2, p, 4.89352455891786e-03f);
  p = __fmul_rn(xc, p);
  float q = __fmaf_rn(x2, 1.19825839466702e-06f, 1.18534705686654e-04f);
  q = __fmaf_rn(x2, q, 2.26843463243900e-03f);
  q = __fmaf_rn(x2, q, 4.89352518554385e-03f);
  float r = __fdiv_rn(p, q);
  return (fabsf(x) < 0.0004f) ? x : r;
}

// ---------------------------------------------------------------------------
// K1: xp = X @ Ux + bh. Per element: single-acc ascending-i FMA chain
// (Eigen order), then one fadd for bias. BIT-EXACT — do not reorder.
// ---------------------------------------------------------------------------
__global__ __launch_bounds__(256) void xp_dot_kernel(
    const float* __restrict__ X, const float* __restrict__ Ux,
    const float* __restrict__ bh, float* __restrict__ XP) {
  __shared__ float xs[8][256];

  const int tid = threadIdx.x;
  const size_t row0 = (size_t)blockIdx.x * 8;

  const float4* src = (const float4*)(X + row0 * 256);
  float4* dst = (float4*)&xs[0][0];
  dst[tid] = src[tid];
  dst[256 + tid] = src[256 + tid];
  __syncthreads();

  const int h = tid;
  float acc[8] = {0.f, 0.f, 0.f, 0.f, 0.f, 0.f, 0.f, 0.f};

#pragma unroll 4
  for (int i = 0; i < 256; ++i) {
    float u = Ux[i * 256 + h];
#pragma unroll
    for (int r = 0; r < 8; ++r)
      acc[r] = __fmaf_rn(xs[r][i], u, acc[r]);   // ascending i, single acc
  }

  const float b = bh[h];
#pragma unroll
  for (int r = 0; r < 8; ++r)
    XP[(row0 + r) * 256 + h] = __fadd_rn(acc[r], b);
}

// ---------------------------------------------------------------------------
// K2: scan. One block per batch row; thread j owns column j. Wh[:,j] in 64
// NAMED float4 registers, made OPAQUE via asm so they cannot be
// rematerialized. waves_per_eu(1,1) lifts the VGPR cap to 512.
// ---------------------------------------------------------------------------
#define DCL(A,B) float4 wq##A##B;
#define DCLROW(A) DCL(A,0) DCL(A,1) DCL(A,2) DCL(A,3) DCL(A,4) DCL(A,5) DCL(A,6) DCL(A,7)

#define LDW(A,B) { const int k0 = ((A)*8+(B))*4; \
  wq##A##B.x = Wh[(k0+0)*256 + j]; \
  wq##A##B.y = Wh[(k0+1)*256 + j]; \
  wq##A##B.z = Wh[(k0+2)*256 + j]; \
  wq##A##B.w = Wh[(k0+3)*256 + j]; }
#define LDWROW(A) LDW(A,0) LDW(A,1) LDW(A,2) LDW(A,3) LDW(A,4) LDW(A,5) LDW(A,6) LDW(A,7)

// Opaque barrier: compiler loses the memory provenance of the values, so it
// must keep them in registers (cannot re-load). Zero runtime cost.
#define OPQ(A,B) asm volatile("" : "+v"(wq##A##B.x), "+v"(wq##A##B.y), \
                                   "+v"(wq##A##B.z), "+v"(wq##A##B.w));
#define OPQROW(A) OPQ(A,0) OPQ(A,1) OPQ(A,2) OPQ(A,3) OPQ(A,4) OPQ(A,5) OPQ(A,6) OPQ(A,7)

#define ACC4(A,B) { float4 hv = h4[(A)*8+(B)]; \
  acc = __fmaf_rn(hv.x, wq##A##B.x, acc); \
  acc = __fmaf_rn(hv.y, wq##A##B.y, acc); \
  acc = __fmaf_rn(hv.z, wq##A##B.z, acc); \
  acc = __fmaf_rn(hv.w, wq##A##B.w, acc); }
#define ACCROW(A) ACC4(A,0) ACC4(A,1) ACC4(A,2) ACC4(A,3) ACC4(A,4) ACC4(A,5) ACC4(A,6) ACC4(A,7)

__global__ __launch_bounds__(256)
__attribute__((amdgpu_waves_per_eu(1, 1)))
void scan_xla_kernel(
    const float* __restrict__ Wh, const float* __restrict__ h0,
    float* __restrict__ xpH, float* __restrict__ hfinal) {
  __shared__ float hbuf0[256];
  __shared__ float hbuf1[256];

  const int b = blockIdx.x;
  const int j = threadIdx.x;

  DCLROW(0) DCLROW(1) DCLROW(2) DCLROW(3)
  DCLROW(4) DCLROW(5) DCLROW(6) DCLROW(7)

  LDWROW(0) LDWROW(1) LDWROW(2) LDWROW(3)
  LDWROW(4) LDWROW(5) LDWROW(6) LDWROW(7)

  OPQROW(0) OPQROW(1) OPQROW(2) OPQROW(3)
  OPQROW(4) OPQROW(5) OPQROW(6) OPQROW(7)

  hbuf0[j] = h0[b * 256 + j];
  __syncthreads();

  float xp_cur = xpH[(size_t)b * 256 + j];  // xp[t=0]
  float hn_prev = 0.f;                      // h_{t-1}[j], valid for t>=1
  const float* cur = hbuf0;
  float* nxt = hbuf1;

  for (int t = 0; t < SEQ; ++t) {
    // Issue previous h-store and next xp-load FIRST: HBM latency retires
    // under the ~1024-cyc dependent FMA chain below.
    if (t > 0)
      xpH[(size_t)(t - 1) * BH + b * 256 + j] = hn_prev;
    float xp_next = (t + 1 < SEQ) ? xpH[(size_t)(t + 1) * BH + b * 256 + j] : 0.f;

    // (h @ Wh)[j]: single acc, ascending k — BIT-EXACT order.
    float acc = 0.f;
    const float4* h4 = (const float4*)cur;
    ACCROW(0) ACCROW(1) ACCROW(2) ACCROW(3)
    ACCROW(4) ACCROW(5) ACCROW(6) ACCROW(7)

    float z = __fadd_rn(xp_cur, acc);
    float hn = tanh_xla(z);

    nxt[j] = hn;          // write to the buffer nobody reads this step
    __syncthreads();      // one barrier per step

    const float* tmp = cur; cur = nxt; nxt = (float*)tmp;
    xp_cur = xp_next;
    hn_prev = hn;
  }

  xpH[(size_t)(SEQ - 1) * BH + b * 256 + j] = hn_prev;
  hfinal[b * 256 + j] = hn_prev;
}

// ---------------------------------------------------------------------------
// K3: in-place fp32 GEMM: rows of HO (M x 256) -> row @ Vo + co.
// Outside the feedback loop => rounding free. Block stages its own 64 rows
// in LDS then overwrites exactly those rows (race-free).
// ---------------------------------------------------------------------------
__global__ __launch_bounds__(256) void gemm_inplace_kernel(
    float* __restrict__ HO, const float* __restrict__ Vo,
    const float* __restrict__ co) {
  __shared__ float Hs[64][260];
  __shared__ float Bs[32][64];

  const int tid = threadIdx.x;
  const int bm = blockIdx.x;
  float* base = HO + (size_t)bm * 64 * 256;

#pragma unroll
  for (int l = 0; l < 16; ++l) {
    int idx = l * 256 + tid;
    int r = idx >> 6;
    int c4 = idx & 63;
    float4 v = *(const float4*)&base[r * 256 + c4 * 4];
    *(float4*)&Hs[r][c4 * 4] = v;
  }

  const int tr = tid >> 4;
  const int tc = tid & 15;

  for (int bn = 0; bn < 4; ++bn) {
    float acc[4][4];
#pragma unroll
    for (int i = 0; i < 4; ++i)
#pragma unroll
      for (int j = 0; j < 4; ++j) acc[i][j] = 0.f;

    for (int kt = 0; kt < 256; kt += 32) {
      __syncthreads();
#pragma unroll
      for (int l = 0; l < 2; ++l) {
        int idx = tid * 2 + l;
        int k2 = idx >> 4;
        int nn = (idx & 15) << 2;
        float4 bv = *(const float4*)&Vo[(size_t)(kt + k2) * 256 + bn * 64 + nn];
        *(float4*)&Bs[k2][nn] = bv;
      }
      __syncthreads();
#pragma unroll
      for (int k = 0; k < 32; ++k) {
        float4 bq = *(const float4*)&Bs[k][tc * 4];
        float bv[4] = {bq.x, bq.y, bq.z, bq.w};
#pragma unroll
        for (int i = 0; i < 4; ++i) {
          float a = Hs[tr * 4 + i][kt + k];
#pragma unroll
          for (int j = 0; j < 4; ++j) acc[i][j] += a * bv[j];
        }
      }
    }

    const float4 cb = *(const float4*)&co[bn * 64 + tc * 4];
    const float cv[4] = {cb.x, cb.y, cb.z, cb.w};
#pragma unroll
    for (int i = 0; i < 4; ++i) {
      float4 o;
      o.x = acc[i][0] + cv[0];
      o.y = acc[i][1] + cv[1];
      o.z = acc[i][2] + cv[2];
      o.w = acc[i][3] + cv[3];
      *(float4*)&base[(tr * 4 + i) * 256 + bn * 64 + tc * 4] = o;
    }
  }
}

extern "C" void kernel_launch(void* const* d_in, const int* in_sizes, int n_in,
                              void* d_out, int out_size, void* d_ws, size_t ws_size,
                              hipStream_t stream) {
  const float* inputs = (const float*)d_in[0];
  const float* h0     = (const float*)d_in[1];
  const float* Wh     = (const float*)d_in[2];
  const float* Ux     = (const float*)d_in[3];
  const float* bh     = (const float*)d_in[4];
  const float* Vo     = (const float*)d_in[5];
  const float* co     = (const float*)d_in[6];

  float* out = (float*)d_out;                       // outputs (S,B,O)
  float* hfinal = out + (size_t)SEQ * BATCH * 256;  // ht_final (B,H)
  (void)d_ws; (void)ws_size;

  const int M = SEQ * BATCH;  // 131072 rows

  // K1: xp (Eigen-order FMA chain + bias add) -> d_out outputs region
  xp_dot_kernel<<<M / 8, 256, 0, stream>>>(inputs, Ux, bh, out);

  // K2: XLA-exact scan, weights pinned in VGPRs.
  scan_xla_kernel<<<BATCH, 256, 0, stream>>>(Wh, h0, out, hfinal);

  // K3: in-place outputs = H @ Vo + co.
  gemm_inplace_kernel<<<M / 64, 256, 0, stream>>>(out, Vo, co);
}